// Round 5
// baseline (150.230 us; speedup 1.0000x reference)
//
#include <hip/hip_runtime.h>

// ---------------------------------------------------------------------------
// DCT-conv:  out = IDCT_H( circconv_W( DCT_H(x), DCT_H(pad(w)) ) summed over ci ) + bias
// B=8, c_in=64, c_out=128, H=W=128, kh=kw=5.
//
// Pipeline (all fp16 storage, fp32 MFMA accumulate):
//   k_wd   : D/M matrices + WD blocked [k][s=10][co=128][kk=32]
//   k_dctH : xd[k][b][ci][w] = D @ x[b][ci]       (512 wgs; D from global/L1)
//   k_conv : y2[b][k][co][w] = sum_{j,ci} WD * xd shifted  (1024 wgs, b-major)
//   k_idct : out[b][co][h][w] = M @ y2 + bias     (1024 wgs; M from global/L1)
//
// All GEMMs compute the TRANSPOSED tile via mfma(bf, af) so each lane's 4 acc
// elements are 4 consecutive w -> wide stores (half4 / f32x4), not 2B scalars.
// ---------------------------------------------------------------------------

using half8v = __attribute__((ext_vector_type(8))) _Float16;
using half4v = __attribute__((ext_vector_type(4))) _Float16;
using f32x4  = __attribute__((ext_vector_type(4))) float;

#define PI_F 3.14159265358979323846f

// XOR-swizzled LDS offset for [n][K] layouts (16B chunks of 8 fp16).
__device__ __forceinline__ int sw_off(int n, int k, int K, int mask) {
    int c = k >> 3;
    return n * K + (((c ^ (n & mask)) << 3) | (k & 7));
}

// ---------------------------------------------------------------------------
// k_wd: wgs 0..255 each handle (co = bid>>1, k-half = bid&1); wgs 0..127 also
// emit the D/M DCT matrices (tiny side job, no intra-kernel consumer).
__global__ __launch_bounds__(256) void k_wd(const float* __restrict__ w,
                                            _Float16* __restrict__ WD,
                                            _Float16* __restrict__ D,
                                            _Float16* __restrict__ M) {
    __shared__ float lw[1600];      // w[co][ci][i][j]  (64*5*5)
    __shared__ float lcos[320];     // 2*cos(pi(2i+1)(k0+kl)/256), [kl][i]
    int bid = blockIdx.x;
    int co = bid >> 1, k0 = (bid & 1) << 6;
    int tid = threadIdx.x;

    if (bid < 128 && tid < 128) {
        int k = bid, h = tid;
        float ang = PI_F * (float)((2 * h + 1) * k) * (1.0f / 256.0f);
        float c = cosf(ang);
        D[k * 128 + h] = (_Float16)(2.0f * c);
        float wk = (k == 0) ? 0.5f : 1.0f;
        M[h * 128 + k] = (_Float16)(c * wk * (1.0f / 256.0f));
    }

    for (int e = tid; e < 1600; e += 256) lw[e] = w[co * 1600 + e];
    for (int e = tid; e < 320; e += 256) {
        int kl = e / 5, i = e - kl * 5;
        lcos[e] = 2.0f * cosf(PI_F * (float)((2 * i + 1) * (k0 + kl)) * (1.0f / 256.0f));
    }
    __syncthreads();

    for (int e = tid; e < 20480; e += 256) {
        int kk = e & 31, rest = e >> 5;
        int s = rest % 10, kl = rest / 10;
        int j = s >> 1, ci = ((s & 1) << 5) + kk;
        const float* wp = &lw[ci * 25 + j];
        const float* cp = &lcos[kl * 5];
        float acc = 0.f;
#pragma unroll
        for (int i = 0; i < 5; ++i) acc += cp[i] * wp[i * 5];
        WD[(((long)(k0 + kl) * 10 + s) * 128 + co) * 32 + kk] = (_Float16)acc;
    }
}

// ---------------------------------------------------------------------------
// Transposed-output GEMM core: A read directly from global (row-major [m][128],
// L1/L2-hot), B from swizzled LDS [n=w][128]. mfma(bf, af) -> per lane:
// m-entity = tile + (lane&15), w = tile + (lane>>4)*4 + reg  (4 consecutive w).
__device__ __forceinline__ void gemm128_gA_T(const _Float16* __restrict__ gA,
                                             const _Float16* lB,
                                             f32x4 acc[4][4], int tid) {
    int lane = tid & 63, ln = lane & 15, q = lane >> 4;
    int wave = tid >> 6, wm = wave >> 1, wn = wave & 1;
#pragma unroll
    for (int s = 0; s < 4; ++s) {
        half8v af[4], bf[4];
#pragma unroll
        for (int mt = 0; mt < 4; ++mt) {
            int m = wm * 64 + mt * 16 + ln;
            af[mt] = *(const half8v*)(&gA[m * 128 + (s * 4 + q) * 8]);
        }
#pragma unroll
        for (int nt = 0; nt < 4; ++nt) {
            int n = wn * 64 + nt * 16 + ln;
            bf[nt] = *(const half8v*)(&lB[n * 128 + (((s * 4 + q) ^ (n & 15)) << 3)]);
        }
#pragma unroll
        for (int mt = 0; mt < 4; ++mt)
#pragma unroll
            for (int nt = 0; nt < 4; ++nt)
                acc[mt][nt] = __builtin_amdgcn_mfma_f32_16x16x32_f16(bf[nt], af[mt], acc[mt][nt], 0, 0, 0);
    }
}

// Transpose-stage fp16 source rows [k][128 w] into swizzled LDS [n=w][K=64].
__device__ __forceinline__ void stage_transB64(const _Float16* __restrict__ src, int row_stride,
                                               _Float16* l, int tid) {
    int kb = tid >> 4, wb = tid & 15;
    int k0 = kb * 4, w0 = wb * 8;
    half8v r0 = *(const half8v*)(&src[(k0 + 0) * row_stride + w0]);
    half8v r1 = *(const half8v*)(&src[(k0 + 1) * row_stride + w0]);
    half8v r2 = *(const half8v*)(&src[(k0 + 2) * row_stride + w0]);
    half8v r3 = *(const half8v*)(&src[(k0 + 3) * row_stride + w0]);
#pragma unroll
    for (int dw = 0; dw < 8; ++dw) {
        int n = w0 + dw;
        half4v p = {r0[dw], r1[dw], r2[dw], r3[dw]};
        *(half4v*)(&l[sw_off(n, k0, 64, 7)]) = p;
    }
}

// Same for K=128 (512 blocks): both 4-load groups hoisted (8 loads in flight).
__device__ __forceinline__ void stage_transB128(const _Float16* __restrict__ src, int row_stride,
                                                _Float16* l, int tid) {
    int blkA = tid, blkB = tid + 256;
    int kA = (blkA >> 4) * 4, wA = (blkA & 15) * 8;
    int kB = (blkB >> 4) * 4, wB = (blkB & 15) * 8;
    half8v a0 = *(const half8v*)(&src[(kA + 0) * row_stride + wA]);
    half8v a1 = *(const half8v*)(&src[(kA + 1) * row_stride + wA]);
    half8v a2 = *(const half8v*)(&src[(kA + 2) * row_stride + wA]);
    half8v a3 = *(const half8v*)(&src[(kA + 3) * row_stride + wA]);
    half8v b0 = *(const half8v*)(&src[(kB + 0) * row_stride + wB]);
    half8v b1 = *(const half8v*)(&src[(kB + 1) * row_stride + wB]);
    half8v b2 = *(const half8v*)(&src[(kB + 2) * row_stride + wB]);
    half8v b3 = *(const half8v*)(&src[(kB + 3) * row_stride + wB]);
#pragma unroll
    for (int dw = 0; dw < 8; ++dw) {
        half4v p = {a0[dw], a1[dw], a2[dw], a3[dw]};
        *(half4v*)(&l[sw_off(wA + dw, kA, 128, 15)]) = p;
    }
#pragma unroll
    for (int dw = 0; dw < 8; ++dw) {
        half4v p = {b0[dw], b1[dw], b2[dw], b3[dw]};
        *(half4v*)(&l[sw_off(wB + dw, kB, 128, 15)]) = p;
    }
}

// ---------------------------------------------------------------------------
// Step A: xd[k][b][ci][w] = sum_h D[k][h] * x[b][ci][h][w]
__global__ __launch_bounds__(256) void k_dctH(const float* __restrict__ x,
                                              const _Float16* __restrict__ Dg,
                                              _Float16* __restrict__ xd) {
    __shared__ _Float16 lB[128 * 128];     // 32 KB
    int b = blockIdx.x >> 6, ci = blockIdx.x & 63;
    int tid = threadIdx.x;

    const float* xs = x + (long)(b * 64 + ci) * 16384;
#pragma unroll
    for (int rep = 0; rep < 2; ++rep) {
        int blk = tid + rep * 256;
        int hb = blk >> 4, wb = blk & 15;
        int h0 = hb * 4, w0 = wb * 8;
        f32x4 f[4][2];
#pragma unroll
        for (int dh = 0; dh < 4; ++dh) {
            f[dh][0] = *(const f32x4*)(&xs[(h0 + dh) * 128 + w0]);
            f[dh][1] = *(const f32x4*)(&xs[(h0 + dh) * 128 + w0 + 4]);
        }
#pragma unroll
        for (int dw = 0; dw < 8; ++dw) {
            int n = w0 + dw;
            half4v p = {(_Float16)f[0][dw >> 2][dw & 3], (_Float16)f[1][dw >> 2][dw & 3],
                        (_Float16)f[2][dw >> 2][dw & 3], (_Float16)f[3][dw >> 2][dw & 3]};
            *(half4v*)(&lB[sw_off(n, h0, 128, 15)]) = p;
        }
    }
    __syncthreads();

    f32x4 acc[4][4] = {};
    gemm128_gA_T(Dg, lB, acc, tid);

    int lane = tid & 63, ln = lane & 15, q = lane >> 4;
    int wave = tid >> 6, wm = wave >> 1, wn = wave & 1;
#pragma unroll
    for (int mt = 0; mt < 4; ++mt)
#pragma unroll
        for (int nt = 0; nt < 4; ++nt) {
            int kk = wm * 64 + mt * 16 + ln;
            int w0 = wn * 64 + nt * 16 + q * 4;
            half4v p = {(_Float16)acc[mt][nt][0], (_Float16)acc[mt][nt][1],
                        (_Float16)acc[mt][nt][2], (_Float16)acc[mt][nt][3]};
            *(half4v*)(&xd[((long)(kk * 8 + b) * 64 + ci) * 128 + w0]) = p;
        }
}

// ---------------------------------------------------------------------------
// Step B: per (k,b):  y2[b][k][co][w] = sum_{s,kk} WD[k][s][co][kk] * xd[k][b][ci][(w-j)&127]
// b-major grid keeps the 80 KB WD k-tile L2-resident across the 8 batches.
// WD A-fragments read directly from global; barrier-free 10-stage loop.
__global__ __launch_bounds__(256) void k_conv(const _Float16* __restrict__ xd,
                                              const _Float16* __restrict__ WD,
                                              _Float16* __restrict__ y2) {
    __shared__ _Float16 lX[128 * 64];        // [w][ci] swizzled, mask=7   (16 KB)
    int bid = blockIdx.x;
    int k = bid & 127, b = bid >> 7;
    int tid = threadIdx.x;

    const _Float16* xs = xd + (long)(k * 8 + b) * 8192;
    stage_transB64(xs, 128, lX, tid);
    __syncthreads();

    int lane = tid & 63, ln = lane & 15, q = lane >> 4;
    int wave = tid >> 6, wm = wave >> 1, wn = wave & 1;
    f32x4 acc[4][4] = {};

    const _Float16* wkb = WD + (long)k * 40960;   // k * 10 * 4096

    for (int s = 0; s < 10; ++s) {
        int j = s >> 1;
        int cb = (s & 1) << 2;   // ci-chunk base within K=64
        const _Float16* wt = wkb + s * 4096;
        half8v af[4], bf[4];
#pragma unroll
        for (int mt = 0; mt < 4; ++mt) {
            int m = wm * 64 + mt * 16 + ln;
            af[mt] = *(const half8v*)(&wt[m * 32 + q * 8]);   // global, L2-hot
        }
#pragma unroll
        for (int nt = 0; nt < 4; ++nt) {
            int wcol = wn * 64 + nt * 16 + ln;
            int n = (wcol - j) & 127;
            bf[nt] = *(const half8v*)(&lX[n * 64 + (((cb + q) ^ (n & 7)) << 3)]);
        }
#pragma unroll
        for (int mt = 0; mt < 4; ++mt)
#pragma unroll
            for (int nt = 0; nt < 4; ++nt)
                acc[mt][nt] = __builtin_amdgcn_mfma_f32_16x16x32_f16(bf[nt], af[mt], acc[mt][nt], 0, 0, 0);
    }

    _Float16* yb = y2 + (long)(b * 128 + k) * 16384;
#pragma unroll
    for (int mt = 0; mt < 4; ++mt)
#pragma unroll
        for (int nt = 0; nt < 4; ++nt) {
            int co = wm * 64 + mt * 16 + ln;
            int w0 = wn * 64 + nt * 16 + q * 4;
            half4v p = {(_Float16)acc[mt][nt][0], (_Float16)acc[mt][nt][1],
                        (_Float16)acc[mt][nt][2], (_Float16)acc[mt][nt][3]};
            *(half4v*)(&yb[co * 128 + w0]) = p;
        }
}

// ---------------------------------------------------------------------------
// Step C: out[b][co][h][w] = sum_k M[h][k] * y2[b][k][co][w] + bias[co]
__global__ __launch_bounds__(256) void k_idct(const _Float16* __restrict__ y2,
                                              const _Float16* __restrict__ Mg,
                                              const float* __restrict__ bias,
                                              float* __restrict__ out) {
    __shared__ _Float16 lB[128 * 128];     // 32 KB
    int b = blockIdx.x >> 7, co = blockIdx.x & 127;
    int tid = threadIdx.x;

    const _Float16* src = y2 + (long)b * 2097152 + co * 128;
    stage_transB128(src, 16384, lB, tid);
    __syncthreads();

    f32x4 acc[4][4] = {};
    gemm128_gA_T(Mg, lB, acc, tid);

    float bv = bias[co];
    float* ob = out + ((long)(b * 128 + co)) * 16384;
    int lane = tid & 63, ln = lane & 15, q = lane >> 4;
    int wave = tid >> 6, wm = wave >> 1, wn = wave & 1;
#pragma unroll
    for (int mt = 0; mt < 4; ++mt)
#pragma unroll
        for (int nt = 0; nt < 4; ++nt) {
            int h = wm * 64 + mt * 16 + ln;
            int w0 = wn * 64 + nt * 16 + q * 4;
            f32x4 p = {acc[mt][nt][0] + bv, acc[mt][nt][1] + bv,
                       acc[mt][nt][2] + bv, acc[mt][nt][3] + bv};
            *(f32x4*)(&ob[h * 128 + w0]) = p;
        }
}

// ---------------------------------------------------------------------------
extern "C" void kernel_launch(void* const* d_in, const int* in_sizes, int n_in,
                              void* d_out, int out_size, void* d_ws, size_t ws_size,
                              hipStream_t stream) {
    const float* x    = (const float*)d_in[0];  // [8][64][128][128]
    const float* w    = (const float*)d_in[1];  // [128][64][5][5]
    const float* bias = (const float*)d_in[2];  // [128]
    float* out = (float*)d_out;                 // [8][128][128][128]

    char* ws = (char*)d_ws;
    _Float16* D  = (_Float16*)(ws);                                  //  32 KB
    _Float16* M  = (_Float16*)(ws + 32768);                          //  32 KB
    _Float16* WD = (_Float16*)(ws + 65536);                          //  10.0 MB
    _Float16* xd = (_Float16*)(ws + 65536 + 10485760);               //  16 MB
    _Float16* y2 = (_Float16*)(ws + 65536 + 10485760 + 16777216);    //  32 MB

    k_wd  <<<dim3(256),  dim3(256), 0, stream>>>(w, WD, D, M);
    k_dctH<<<dim3(512),  dim3(256), 0, stream>>>(x, D, xd);
    k_conv<<<dim3(1024), dim3(256), 0, stream>>>(xd, WD, y2);
    k_idct<<<dim3(1024), dim3(256), 0, stream>>>(y2, M, bias, out);
}